// Round 10
// baseline (45.948 us; speedup 1.0000x reference)
//
#include <hip/hip_runtime.h>

// ---------------- types / helpers ----------------
typedef short bf16x8 __attribute__((ext_vector_type(8)));
typedef float f32x4  __attribute__((ext_vector_type(4)));

// ws layout (floats): [0,30720) = Apack (61440 bf16 = 20 ksteps * 6144 B)
//                     [30720,30816) = cst96, [30816,30822) = qbias
#define WS_CONST 30720
#define WS_QBIAS 30816

__device__ __forceinline__ short f2bf(float f) {
    unsigned u = __float_as_uint(f);
    unsigned r = (u + 0x7FFFu + ((u >> 16) & 1u)) >> 16;  // RNE
    return (short)r;
}

// ---------------- prep (R9 version, unchanged) ----------------
__global__ __launch_bounds__(256) void prep_kernel(
    const float* __restrict__ W_query, const float* __restrict__ b_query,
    const float* __restrict__ W_x,     const float* __restrict__ b_x,
    const float* __restrict__ W_ret0,  const float* __restrict__ b_ret0,
    const float* __restrict__ W_ret1,  const float* __restrict__ b_ret1,
    const float* __restrict__ W_ret2,  const float* __restrict__ b_ret2,
    const float* __restrict__ W_pred,  const float* __restrict__ b_pred,
    const float* __restrict__ angles,  const int* __restrict__ wires,
    float* __restrict__ ws)
{
    const int bid = blockIdx.x;
    const int t = threadIdx.x;
    __shared__ float wp[3072];   // W_pred slab [32 rows][96 k]
    __shared__ float wsl[768];   // slice [96 k][8 s]
    short* ap = (short*)ws;

    if (bid < 240) {
        const int rg = bid % 3;              // row group (32 rows)
        const int cg = bid / 3;              // col group (8 cols); <64 = M1, else M2
        const bool isM1 = cg < 64;
        const int off = isM1 ? 0 : 96;
        #pragma unroll
        for (int i = 0; i < 12; ++i) {
            int L = t + i * 256;             // 0..3071
            int r = L / 96, k = L - r * 96;
            wp[L] = W_pred[(rg * 32 + r) * 192 + off + k];
        }
        if (isM1) {
            const int s0 = cg * 8;
            #pragma unroll
            for (int i = 0; i < 3; ++i) {
                int L = t + i * 256;
                int k = L >> 3, s = L & 7;
                wsl[L] = W_x[k * 512 + s0 + s];
            }
        } else {
            const int j0 = (cg - 64) * 8;
            #pragma unroll
            for (int i = 0; i < 3; ++i) {
                int L = t + i * 256;
                int k = L >> 3, jj = L & 7;
                int j = j0 + jj;
                float v = 0.f;
                if (j < 104) {
                    const float* Wr; int d, jl;
                    if (j < 48)      { Wr = W_ret0; d = 48; jl = j; }
                    else if (j < 80) { Wr = W_ret1; d = 32; jl = j - 48; }
                    else             { Wr = W_ret2; d = 24; jl = j - 80; }
                    v = Wr[k * d + jl];
                }
                wsl[L] = v;
            }
        }
        __syncthreads();
        const int rl = t >> 3, s = t & 7;
        float acc = 0.f;
        #pragma unroll 8
        for (int k = 0; k < 96; ++k) acc += wp[rl * 96 + k] * wsl[k * 8 + s];
        const int r = rg * 32 + rl;
        const int sg = isM1 ? (cg * 8 + s) : (512 + (cg - 64) * 8 + s);
        const int kstep = sg >> 5, s32 = sg & 31;
        const int g = s32 >> 3, e = s32 & 7;
        ap[kstep * 3072 + (r >> 4) * 512 + (g * 16 + (r & 15)) * 8 + e] = f2bf(acc);
    } else {
        if (t < 96) {
            float v = b_pred[t];
            for (int k = 0; k < 96; ++k) {
                v += W_pred[t * 192 + k] * b_x[k];
                v += W_pred[t * 192 + 96 + k] * (b_ret0[k] + b_ret1[k] + b_ret2[k]);
            }
            ws[WS_CONST + t] = v;
        } else if (t < 102) {
            int w = t - 96;
            float v = b_query[w];
            for (int k = 0; k < 18; ++k)
                if (wires[k] == w) v += angles[k];
            ws[WS_QBIAS + w] = v;
        }
    }
}

// ---------------- main kernel (R5/R9 verified version, unchanged) ----------------
__global__ __launch_bounds__(512) void main_kernel(
    const float* __restrict__ x_enc,
    const int*   __restrict__ index,
    const float* __restrict__ W_query,
    const float* __restrict__ W_prob,
    const float* __restrict__ b_prob,
    const float* __restrict__ RT,
    const float* __restrict__ gumbel,
    const float* __restrict__ ws,
    float* __restrict__ out)
{
    const int bid = blockIdx.x;
    const int b = bid & 127;
    const int cbase = (bid >> 7) * 16;
    const int t = threadIdx.x;
    const int lane = t & 63;
    const int wv = t >> 6;

    __shared__ __align__(16) union {
        struct { float wq[3072]; float qp[3072]; } s0;
        char Abuf[24576];
    } u0;
    __shared__ __align__(16) short xbuf[16][520];
    __shared__ __align__(16) union {
        float qfin[96];
        short selbuf[16][136];
    } u1;
    __shared__ int m_sel[16];

    const float* __restrict__ xb = x_enc + (size_t)b * 32768;

    {
        const float4* wsrc = (const float4*)W_query;
        float4* wdst = (float4*)u0.s0.wq;
        for (int L = t; L < 768; L += 512) wdst[L] = wsrc[L];
    }

    const int c  = t & 15;
    const int sg = t >> 4;
    const float xo = xb[511 * 64 + cbase + c];
    const float* xs = xb + (size_t)(sg * 16) * 64 + cbase + c;
    float v[16];
    #pragma unroll
    for (int i = 0; i < 16; ++i) v[i] = xs[i * 64];

    __syncthreads();

    {
        #pragma unroll
        for (int i = 0; i < 16; ++i) v[i] -= xo;
        const float4* wq4 = (const float4*)u0.s0.wq;
        float* qp = u0.s0.qp;
        #pragma unroll
        for (int wr = 0; wr < 6; ++wr) {
            float a = 0.f;
            #pragma unroll
            for (int i4 = 0; i4 < 4; ++i4) {
                float4 w4 = wq4[wr * 128 + sg * 4 + i4];
                a += w4.x * v[i4*4+0] + w4.y * v[i4*4+1] + w4.z * v[i4*4+2] + w4.w * v[i4*4+3];
            }
            qp[sg * 96 + wr * 16 + c] = a;
        }
        short* xrow = &xbuf[c][sg * 16];
        #pragma unroll
        for (int i = 0; i < 16; i += 2) {
            unsigned lo = (unsigned short)f2bf(v[i]);
            unsigned hi = (unsigned short)f2bf(v[i+1]);
            *(unsigned*)&xrow[i] = lo | (hi << 16);
        }
    }
    __syncthreads();

    if (t < 96) {
        int w6 = t >> 4, cc = t & 15;
        const float* qp = u0.s0.qp;
        float s = 0.f;
        #pragma unroll
        for (int g2 = 0; g2 < 32; ++g2) s += qp[g2 * 96 + w6 * 16 + cc];
        u1.qfin[w6 * 16 + cc] = s;
    }
    __syncthreads();

    if (t < 16) {
        float e[6];
        #pragma unroll
        for (int w = 0; w < 6; ++w) e[w] = cosf(u1.qfin[w * 16 + t] + ws[WS_QBIAS + w]);
        int grow = (b * 64 + cbase + t) * 4;
        float best = -1e30f; int bm = 0;
        #pragma unroll
        for (int m = 0; m < 4; ++m) {
            float lg = b_prob[m];
            #pragma unroll
            for (int w = 0; w < 6; ++w) lg += W_prob[m * 6 + w] * e[w];
            lg += gumbel[grow + m];
            if (lg > best) { best = lg; bm = m; }
        }
        m_sel[t] = bm;
    }
    __syncthreads();

    {
        const int idxb = index[b];
        for (int L = t; L < 16 * 136; L += 512) {
            int cc = L & 15, j = L >> 4;
            short val = 0;
            if (j < 104) {
                int i, row;
                if (j < 48)      { i = 0; row = j * 2; }
                else if (j < 80) { i = 1; row = (j - 48) * 3; }
                else             { i = 2; row = (j - 80) * 4; }
                val = f2bf(RT[(size_t)i * 122880000ull + (size_t)idxb * 24576ull
                             + (size_t)m_sel[cc] * 6144ull + (size_t)row * 64ull + cbase + cc]);
            }
            u1.selbuf[cc][j] = val;
        }
    }

    const char* Apack = (const char*)ws;
    const int cl = lane & 15, g = lane >> 4;
    f32x4 acc0 = {0,0,0,0};
    for (int ch = 0; ch < 5; ++ch) {
        const float4* asrc = (const float4*)(Apack + ch * 24576);
        float4 r0 = asrc[t], r1 = asrc[t + 512], r2 = asrc[t + 1024];
        __syncthreads();
        float4* adst = (float4*)u0.Abuf;
        adst[t] = r0; adst[t + 512] = r1; adst[t + 1024] = r2;
        __syncthreads();
        if (wv < 6) {
            #pragma unroll
            for (int ks = 0; ks < 4; ++ks) {
                bf16x8 av = *(const bf16x8*)(u0.Abuf + ks * 6144 + wv * 1024 + lane * 16);
                bf16x8 bv0;
                if (ch < 4) bv0 = *(const bf16x8*)&xbuf[cl][ch * 128 + ks * 32 + g * 8];
                else        bv0 = *(const bf16x8*)&u1.selbuf[cl][ks * 32 + g * 8];
                acc0 = __builtin_amdgcn_mfma_f32_16x16x32_bf16(av, bv0, acc0, 0, 0, 0);
            }
        }
    }

    if (wv < 6) {
        const float* cst = ws + WS_CONST;
        float xo0 = xb[511 * 64 + cbase + cl];
        int r0 = wv * 16 + g * 4;
        float* op = out + (size_t)b * 6144 + (size_t)r0 * 64 + cbase;
        #pragma unroll
        for (int reg = 0; reg < 4; ++reg)
            op[reg * 64 + cl] = acc0[reg] + cst[r0 + reg] + xo0;
    }
}

extern "C" void kernel_launch(void* const* d_in, const int* in_sizes, int n_in,
                              void* d_out, int out_size, void* d_ws, size_t ws_size,
                              hipStream_t stream) {
    (void)in_sizes; (void)n_in; (void)out_size; (void)ws_size;
    const float* x_enc   = (const float*)d_in[0];
    const int*   index   = (const int*)d_in[1];
    const float* W_query = (const float*)d_in[2];
    const float* b_query = (const float*)d_in[3];
    const float* W_x     = (const float*)d_in[4];
    const float* b_x     = (const float*)d_in[5];
    const float* W_prob  = (const float*)d_in[6];
    const float* b_prob  = (const float*)d_in[7];
    const float* W_ret0  = (const float*)d_in[8];
    const float* b_ret0  = (const float*)d_in[9];
    const float* W_ret1  = (const float*)d_in[10];
    const float* b_ret1  = (const float*)d_in[11];
    const float* W_ret2  = (const float*)d_in[12];
    const float* b_ret2  = (const float*)d_in[13];
    const float* W_pred  = (const float*)d_in[14];
    const float* b_pred  = (const float*)d_in[15];
    const float* RT      = (const float*)d_in[16];
    const float* angles  = (const float*)d_in[17];
    const int*   wires   = (const int*)d_in[18];
    const float* gumbel  = (const float*)d_in[19];
    float* out = (float*)d_out;
    float* ws  = (float*)d_ws;

    prep_kernel<<<241, 256, 0, stream>>>(W_query, b_query, W_x, b_x,
                                         W_ret0, b_ret0, W_ret1, b_ret1, W_ret2, b_ret2,
                                         W_pred, b_pred, angles, wires, ws);
    // MEASUREMENT ROUND: main launched 3x (idempotent — same inputs -> same out).
    // Marginal cost (dur - 24.0)/2 = main's true replay duration.
    main_kernel<<<512, 512, 0, stream>>>(x_enc, index, W_query, W_prob, b_prob,
                                         RT, gumbel, ws, out);
    main_kernel<<<512, 512, 0, stream>>>(x_enc, index, W_query, W_prob, b_prob,
                                         RT, gumbel, ws, out);
    main_kernel<<<512, 512, 0, stream>>>(x_enc, index, W_query, W_prob, b_prob,
                                         RT, gumbel, ws, out);
}

// Round 11
// 23.319 us; speedup vs baseline: 1.9704x; 1.9704x over previous
//
#include <hip/hip_runtime.h>

// ---------------- types / helpers ----------------
typedef short bf16x8 __attribute__((ext_vector_type(8)));
typedef float f32x4  __attribute__((ext_vector_type(4)));

// ws layout (floats): [0,30720) = Apack (61440 bf16 = 20 ksteps * 6144 B)
//                     [30720,30816) = cst96, [30816,30822) = qbias
#define WS_CONST 30720
#define WS_QBIAS 30816

__device__ __forceinline__ short f2bf(float f) {
    unsigned u = __float_as_uint(f);
    unsigned r = (u + 0x7FFFu + ((u >> 16) & 1u)) >> 16;  // RNE
    return (short)r;
}

// ---------------- prep (R9 version, unchanged) ----------------
__global__ __launch_bounds__(256) void prep_kernel(
    const float* __restrict__ W_query, const float* __restrict__ b_query,
    const float* __restrict__ W_x,     const float* __restrict__ b_x,
    const float* __restrict__ W_ret0,  const float* __restrict__ b_ret0,
    const float* __restrict__ W_ret1,  const float* __restrict__ b_ret1,
    const float* __restrict__ W_ret2,  const float* __restrict__ b_ret2,
    const float* __restrict__ W_pred,  const float* __restrict__ b_pred,
    const float* __restrict__ angles,  const int* __restrict__ wires,
    float* __restrict__ ws)
{
    const int bid = blockIdx.x;
    const int t = threadIdx.x;
    __shared__ float wp[3072];   // W_pred slab [32 rows][96 k]
    __shared__ float wsl[768];   // slice [96 k][8 s]
    short* ap = (short*)ws;

    if (bid < 240) {
        const int rg = bid % 3;              // row group (32 rows)
        const int cg = bid / 3;              // col group (8 cols); <64 = M1, else M2
        const bool isM1 = cg < 64;
        const int off = isM1 ? 0 : 96;
        #pragma unroll
        for (int i = 0; i < 12; ++i) {
            int L = t + i * 256;             // 0..3071
            int r = L / 96, k = L - r * 96;
            wp[L] = W_pred[(rg * 32 + r) * 192 + off + k];
        }
        if (isM1) {
            const int s0 = cg * 8;
            #pragma unroll
            for (int i = 0; i < 3; ++i) {
                int L = t + i * 256;
                int k = L >> 3, s = L & 7;
                wsl[L] = W_x[k * 512 + s0 + s];
            }
        } else {
            const int j0 = (cg - 64) * 8;
            #pragma unroll
            for (int i = 0; i < 3; ++i) {
                int L = t + i * 256;
                int k = L >> 3, jj = L & 7;
                int j = j0 + jj;
                float v = 0.f;
                if (j < 104) {
                    const float* Wr; int d, jl;
                    if (j < 48)      { Wr = W_ret0; d = 48; jl = j; }
                    else if (j < 80) { Wr = W_ret1; d = 32; jl = j - 48; }
                    else             { Wr = W_ret2; d = 24; jl = j - 80; }
                    v = Wr[k * d + jl];
                }
                wsl[L] = v;
            }
        }
        __syncthreads();
        const int rl = t >> 3, s = t & 7;
        float acc = 0.f;
        #pragma unroll 8
        for (int k = 0; k < 96; ++k) acc += wp[rl * 96 + k] * wsl[k * 8 + s];
        const int r = rg * 32 + rl;
        const int sg = isM1 ? (cg * 8 + s) : (512 + (cg - 64) * 8 + s);
        const int kstep = sg >> 5, s32 = sg & 31;
        const int g = s32 >> 3, e = s32 & 7;
        ap[kstep * 3072 + (r >> 4) * 512 + (g * 16 + (r & 15)) * 8 + e] = f2bf(acc);
    } else {
        if (t < 96) {
            float v = b_pred[t];
            for (int k = 0; k < 96; ++k) {
                v += W_pred[t * 192 + k] * b_x[k];
                v += W_pred[t * 192 + 96 + k] * (b_ret0[k] + b_ret1[k] + b_ret2[k]);
            }
            ws[WS_CONST + t] = v;
        } else if (t < 102) {
            int w = t - 96;
            float v = b_query[w];
            for (int k = 0; k < 18; ++k)
                if (wires[k] == w) v += angles[k];
            ws[WS_QBIAS + w] = v;
        }
    }
}

// ---------------- main kernel: 4-barrier restructure ----------------
// grid 512: b = bid&127, c-quarter = bid>>7 (16 cols). 512 threads = 8 waves.
// Changes vs R9 (numerics identical -> absmax canary 0.03125):
//  - W_query read direct from global (L2-hot), no staging barrier
//  - Apack read direct global->VGPR per kstep (each wave's slice is private;
//    LDS staging had zero cross-wave reuse) -> all 10 A-loop barriers gone
//  - RT gather issued into REGISTERS before the x-MFMA, written to LDS after
//    -> gather latency hides under 16 ksteps of MFMA + A-loads
__global__ __launch_bounds__(512) void main_kernel(
    const float* __restrict__ x_enc,
    const int*   __restrict__ index,
    const float* __restrict__ W_query,
    const float* __restrict__ W_prob,
    const float* __restrict__ b_prob,
    const float* __restrict__ RT,
    const float* __restrict__ gumbel,
    const float* __restrict__ ws,
    float* __restrict__ out)
{
    const int bid = blockIdx.x;
    const int b = bid & 127;
    const int cbase = (bid >> 7) * 16;
    const int t = threadIdx.x;
    const int lane = t & 63;
    const int wv = t >> 6;
    const int cl = lane & 15, g = lane >> 4;

    __shared__ __align__(16) union {
        float qp[3072];                      // [32 sg][6 w][16 c] q partials
        short selbuf[16][136];               // [c][j 128+pad] bf16
    } u0;
    __shared__ __align__(16) short xbuf[16][520];   // [c][k 512] bf16
    __shared__ float qfin[96];               // [w6][16]
    __shared__ int m_sel[16];

    const float* __restrict__ xb = x_enc + (size_t)b * 32768;

    // single x pass: thread (c 0..15, sg 0..31) loads 16 rows at column c
    const int c  = t & 15;
    const int sg = t >> 4;
    const float xo = xb[511 * 64 + cbase + c];
    const float* xs = xb + (size_t)(sg * 16) * 64 + cbase + c;
    float v[16];
    #pragma unroll
    for (int i = 0; i < 16; ++i) v[i] = xs[i * 64];

    // fp32 q partials (W_query direct from global, same values/order as staged)
    {
        #pragma unroll
        for (int i = 0; i < 16; ++i) v[i] -= xo;
        const float4* wq4 = (const float4*)W_query;      // [6][128] float4 view
        #pragma unroll
        for (int wr = 0; wr < 6; ++wr) {
            float a = 0.f;
            #pragma unroll
            for (int i4 = 0; i4 < 4; ++i4) {
                float4 w4 = wq4[wr * 128 + sg * 4 + i4]; // uniform per 16-lane group
                a += w4.x * v[i4*4+0] + w4.y * v[i4*4+1] + w4.z * v[i4*4+2] + w4.w * v[i4*4+3];
            }
            u0.qp[sg * 96 + wr * 16 + c] = a;
        }
        short* xrow = &xbuf[c][sg * 16];
        #pragma unroll
        for (int i = 0; i < 16; i += 2) {
            unsigned lo = (unsigned short)f2bf(v[i]);
            unsigned hi = (unsigned short)f2bf(v[i+1]);
            *(unsigned*)&xrow[i] = lo | (hi << 16);
        }
    }
    __syncthreads();   // B1: qp, xbuf ready

    // q reduce over 32 sg-groups
    if (t < 96) {
        int w6 = t >> 4, cc = t & 15;
        const float* qp = u0.qp;
        float s = 0.f;
        #pragma unroll
        for (int g2 = 0; g2 < 32; ++g2) s += qp[g2 * 96 + w6 * 16 + cc];
        qfin[w6 * 16 + cc] = s;
    }
    __syncthreads();   // B2: qfin ready, qp dead

    // argmax (fp32 q path)
    if (t < 16) {
        float e[6];
        #pragma unroll
        for (int w = 0; w < 6; ++w) e[w] = cosf(qfin[w * 16 + t] + ws[WS_QBIAS + w]);
        int grow = (b * 64 + cbase + t) * 4;
        float best = -1e30f; int bm = 0;
        #pragma unroll
        for (int m = 0; m < 4; ++m) {
            float lg = b_prob[m];
            #pragma unroll
            for (int w = 0; w < 6; ++w) lg += W_prob[m * 6 + w] * e[w];
            lg += gumbel[grow + m];          // argmax invariant under /0.5
            if (lg > best) { best = lg; bm = m; }   // first-max like jnp.argmax
        }
        m_sel[t] = bm;
    }
    __syncthreads();   // B3: m_sel ready; qp region reusable as selbuf

    // issue RT gather into registers (latency hides under x-MFMA below)
    const int idxb = index[b];
    float gv[5];
    #pragma unroll
    for (int it = 0; it < 5; ++it) {
        const int L = t + it * 512;
        float val = 0.f;
        if (L < 2176) {
            const int cc = L & 15, j = L >> 4;
            if (j < 104) {
                int i, row;
                if (j < 48)      { i = 0; row = j * 2; }
                else if (j < 80) { i = 1; row = (j - 48) * 3; }
                else             { i = 2; row = (j - 80) * 4; }
                val = RT[(size_t)i * 122880000ull + (size_t)idxb * 24576ull
                         + (size_t)m_sel[cc] * 6144ull + (size_t)row * 64ull + cbase + cc];
            }
        }
        gv[it] = val;
    }

    // x-part MFMA: 16 ksteps, A direct global->VGPR (coalesced, L2-hot, per-wave slice)
    const char* Ap = (const char*)ws;
    f32x4 acc = {0,0,0,0};
    if (wv < 6) {
        #pragma unroll 4
        for (int ks = 0; ks < 16; ++ks) {
            bf16x8 av = *(const bf16x8*)(Ap + ks * 6144 + wv * 1024 + lane * 16);
            bf16x8 bv = *(const bf16x8*)&xbuf[cl][ks * 32 + g * 8];
            acc = __builtin_amdgcn_mfma_f32_16x16x32_bf16(av, bv, acc, 0, 0, 0);
        }
    }

    // write gathered values to selbuf (bf16; j>=104 pads write 0)
    #pragma unroll
    for (int it = 0; it < 5; ++it) {
        const int L = t + it * 512;
        if (L < 2176) {
            const int cc = L & 15, j = L >> 4;
            u0.selbuf[cc][j] = f2bf(gv[it]);
        }
    }
    __syncthreads();   // B4: selbuf ready

    // sel-part MFMA + epilogue
    if (wv < 6) {
        #pragma unroll
        for (int ks = 0; ks < 4; ++ks) {
            bf16x8 av = *(const bf16x8*)(Ap + (16 + ks) * 6144 + wv * 1024 + lane * 16);
            bf16x8 bv = *(const bf16x8*)&u0.selbuf[cl][ks * 32 + g * 8];
            acc = __builtin_amdgcn_mfma_f32_16x16x32_bf16(av, bv, acc, 0, 0, 0);
        }
        // epilogue: D layout col=lane&15, row=4*(lane>>4)+reg (m89-verified)
        const float* cst = ws + WS_CONST;
        float xo0 = xb[511 * 64 + cbase + cl];
        int r0 = wv * 16 + g * 4;
        float* op = out + (size_t)b * 6144 + (size_t)r0 * 64 + cbase;
        #pragma unroll
        for (int reg = 0; reg < 4; ++reg)
            op[reg * 64 + cl] = acc[reg] + cst[r0 + reg] + xo0;
    }
}

extern "C" void kernel_launch(void* const* d_in, const int* in_sizes, int n_in,
                              void* d_out, int out_size, void* d_ws, size_t ws_size,
                              hipStream_t stream) {
    (void)in_sizes; (void)n_in; (void)out_size; (void)ws_size;
    const float* x_enc   = (const float*)d_in[0];
    const int*   index   = (const int*)d_in[1];
    const float* W_query = (const float*)d_in[2];
    const float* b_query = (const float*)d_in[3];
    const float* W_x     = (const float*)d_in[4];
    const float* b_x     = (const float*)d_in[5];
    const float* W_prob  = (const float*)d_in[6];
    const float* b_prob  = (const float*)d_in[7];
    const float* W_ret0  = (const float*)d_in[8];
    const float* b_ret0  = (const float*)d_in[9];
    const float* W_ret1  = (const float*)d_in[10];
    const float* b_ret1  = (const float*)d_in[11];
    const float* W_ret2  = (const float*)d_in[12];
    const float* b_ret2  = (const float*)d_in[13];
    const float* W_pred  = (const float*)d_in[14];
    const float* b_pred  = (const float*)d_in[15];
    const float* RT      = (const float*)d_in[16];
    const float* angles  = (const float*)d_in[17];
    const int*   wires   = (const int*)d_in[18];
    const float* gumbel  = (const float*)d_in[19];
    float* out = (float*)d_out;
    float* ws  = (float*)d_ws;

    prep_kernel<<<241, 256, 0, stream>>>(W_query, b_query, W_x, b_x,
                                         W_ret0, b_ret0, W_ret1, b_ret1, W_ret2, b_ret2,
                                         W_pred, b_pred, angles, wires, ws);
    main_kernel<<<512, 512, 0, stream>>>(x_enc, index, W_query, W_prob, b_prob,
                                         RT, gumbel, ws, out);
}